// Round 4
// baseline (166.304 us; speedup 1.0000x reference)
//
#include <hip/hip_runtime.h>
#include <hip/hip_bf16.h>
#include <hip/hip_fp16.h>

#define N_NODES 100000
#define D 64
#define N_EDGES 1250000

// fine buckets (sortgather granularity)
#define RB 64                   // nodes per fine bucket (dst>>6)
#define NB 1563                 // ceil(N / 64)
#define FCAP 1536               // fine slab capacity; mean 800, max ~950
#define SORT_CAP 1536

// coarse buckets (partition pass A)
#define CB_SHIFT 11             // 2048 nodes per coarse bucket
#define NCB 49                  // ceil(N / 2048)
#define CCAP 28672              // mean 25510, sigma ~158 -> +20 sigma
#define FINE_PER_COARSE 32      // 2048/64

// cursor padding: one counter per 64B cache line (round-1: packed cursors
// shared 4 lines across all blocks' global atomics).
#define CPAD 16                 // ints per cursor slot (64 B)

#define EPB 4096                // edges per pass-A block; 306 blocks >= 1/CU
#define PARTA_BLOCKS ((N_EDGES + EPB - 1) / EPB)   // 306
#define SEGS 16                 // pass-B blocks per coarse bucket

#define TN 64                   // nodes per pre block
#define PRE_BLOCKS 1563         // ceil(N / 64)

#define XP 72                   // LDS fp16 row stride (64 + 8 pad -> 2-way-free b128)

typedef unsigned short ushort_t;
typedef _Float16 half_t;
typedef __attribute__((ext_vector_type(8))) _Float16 half8;
typedef __attribute__((ext_vector_type(4))) float floatx4;

// ---------------------------------------------------------------------------
// Pre-transform (standalone for rocprof attribution):
// [Y|Z] = X @ [W_l|W_r] via fp16 MFMA (fp32 accumulate).
// OPERANDS SWAPPED vs round 2: acc = mfma(W_frag, X_frag) so
//   D[m=outcol][n=node]: col=lane&15 -> node, row=quad*4+reg -> outcol.
// Each lane owns 4 CONSECUTIVE outcols of ONE node -> one packed 8 B store
// per ct (8 stores/thread total, was 32 scalar 2 B stores). Bias for z folds
// in as a float4 read per (ct,quad), hoisted to bq[4].
// Fragment maps (guide §3): A[m=lane&15][k=quad*8+j], B[k=quad*8+j][n=lane&15],
// C/D col=lane&15, row=quad*4+reg.
// ---------------------------------------------------------------------------
__global__ __launch_bounds__(256) void pre_kernel(
    const float* __restrict__ x, const float* __restrict__ W_l,
    const float* __restrict__ b_l, const float* __restrict__ W_r,
    ushort_t* __restrict__ y, ushort_t* __restrict__ z, int N)
{
    __shared__ half_t sWt[128 * XP];   // sWt[col][k] = W[k][col], 18,432 B
    __shared__ half_t sXh[TN * XP];    // sXh[node][k] fp16,        9,216 B
    int t = threadIdx.x;

    // stage W transposed fp16 (W_l -> cols 0..63, W_r -> cols 64..127)
    for (int i = t; i < 64 * 64; i += 256) {
        int k = i >> 6, c = i & 63;
        sWt[c * XP + k]        = (half_t)W_l[i];
        sWt[(64 + c) * XP + k] = (half_t)W_r[i];
    }

    long base = (long)blockIdx.x * TN;
    for (int i = t; i < TN * 16; i += 256) {   // 64 nodes x 16 float4
        int n = i >> 4, q = i & 15;
        long node = base + n;
        float4 v = make_float4(0.f, 0.f, 0.f, 0.f);
        if (node < N) v = ((const float4*)(x + node * D))[q];
        half_t* p = &sXh[n * XP + q * 4];
        p[0] = (half_t)v.x; p[1] = (half_t)v.y;
        p[2] = (half_t)v.z; p[3] = (half_t)v.w;
    }

    const int lane  = t & 63;
    const int w     = t >> 6;        // wave id = node-tile 0..3
    const int col16 = lane & 15;
    const int quad  = lane >> 4;

    // z-bias: bq[j] = b_l[j*16 + quad*4 .. +3], hoisted (L1-resident)
    float4 bq[4];
#pragma unroll
    for (int j = 0; j < 4; j++) bq[j] = *(const float4*)(b_l + j * 16 + quad * 4);

    __syncthreads();

    // X fragment (B operand, n = node within this wave's 16-node tile)
    const int nrow = w * 16 + col16;
    half8 xb0 = *(half8*)&sXh[nrow * XP + quad * 8];
    half8 xb1 = *(half8*)&sXh[nrow * XP + 32 + quad * 8];

    long node = base + nrow;
    bool ok = (node < N);

#pragma unroll 2
    for (int ct = 0; ct < 8; ct++) {
        int c = ct * 16 + col16;                 // A operand m = outcol
        half8 wa0 = *(half8*)&sWt[c * XP + quad * 8];
        half8 wa1 = *(half8*)&sWt[c * XP + 32 + quad * 8];
        floatx4 acc = {0.f, 0.f, 0.f, 0.f};
        acc = __builtin_amdgcn_mfma_f32_16x16x32_f16(wa0, xb0, acc, 0, 0, 0);
        acc = __builtin_amdgcn_mfma_f32_16x16x32_f16(wa1, xb1, acc, 0, 0, 0);

        if (ok) {
            int oc = ct * 16 + quad * 4;         // outcol base 0..124
            union { half_t h[4]; uint2 u; } pk;
            if (ct < 4) {
                pk.h[0] = (half_t)acc[0]; pk.h[1] = (half_t)acc[1];
                pk.h[2] = (half_t)acc[2]; pk.h[3] = (half_t)acc[3];
                *(uint2*)(y + node * D + oc) = pk.u;
            } else {
                float4 bv = bq[ct - 4];
                pk.h[0] = (half_t)(acc[0] + bv.x); pk.h[1] = (half_t)(acc[1] + bv.y);
                pk.h[2] = (half_t)(acc[2] + bv.z); pk.h[3] = (half_t)(acc[3] + bv.w);
                *(uint2*)(z + node * D + (oc - 64)) = pk.u;
            }
        }
    }
}

// ---------------------------------------------------------------------------
// Partition pass A (standalone for attribution): scatter edges into 49
// coarse buckets (dst>>11). Per-wave privatized LDS histograms; one padded
// global atomicAdd per (block, bucket).
// ---------------------------------------------------------------------------
__global__ __launch_bounds__(256) void partA_kernel(
    const int* __restrict__ src, const int* __restrict__ dst,
    int* __restrict__ ccursor, unsigned* __restrict__ coarse, int E)
{
    __shared__ int hist[4][NCB];    // per-wave private histograms
    __shared__ int wbase[4][NCB];   // per-wave write bases
    int t = threadIdx.x;
    const int w = t >> 6;

    if (t < 4 * NCB) ((int*)hist)[t] = 0;
    __syncthreads();

    int base = blockIdx.x * EPB;
    int lim = E - base; if (lim > EPB) lim = EPB;

    for (int i = t; i < lim; i += 256) {
        int d = dst[base + i];
        atomicAdd(&hist[w][d >> CB_SHIFT], 1);
    }
    __syncthreads();

    if (t < NCB) {
        int c0 = hist[0][t], c1 = hist[1][t];
        int c2 = hist[2][t], c3 = hist[3][t];
        int tot = c0 + c1 + c2 + c3;
        int b0 = tot ? atomicAdd(&ccursor[t * CPAD], tot) : 0;
        wbase[0][t] = b0;
        wbase[1][t] = b0 + c0;
        wbase[2][t] = b0 + c0 + c1;
        wbase[3][t] = b0 + c0 + c1 + c2;
    }
    __syncthreads();

    for (int i = t; i < lim; i += 256) {
        int d = dst[base + i];
        int s = src[base + i];
        int b = d >> CB_SHIFT;
        int pos = atomicSub(&hist[w][b], 1) - 1;
        coarse[(size_t)b * CCAP + wbase[w][b] + pos] =
            (unsigned)s | ((unsigned)(d & ((1 << CB_SHIFT) - 1)) << 17);
    }
}

// ---------------------------------------------------------------------------
// Partition pass B: 16 segment-blocks per coarse bucket. Scatters into the 32
// fine buckets inside the coarse bucket. Per-wave privatized histograms;
// padded fcursor. Repacks src | fineLocal<<17.
// ---------------------------------------------------------------------------
__global__ __launch_bounds__(256) void partB_kernel(
    const unsigned* __restrict__ coarse, const int* __restrict__ ccursor,
    int* __restrict__ fcursor, unsigned* __restrict__ fine)
{
    __shared__ int hist[4][FINE_PER_COARSE];
    __shared__ int wbase[4][FINE_PER_COARSE];
    int cb = blockIdx.x >> 4;        // SEGS = 16
    int seg = blockIdx.x & 15;
    int t = threadIdx.x;
    const int w = t >> 6;

    int cnt = ccursor[cb * CPAD];
    int segLen = (cnt + SEGS - 1) / SEGS;
    int beg = seg * segLen;
    int end = beg + segLen; if (end > cnt) end = cnt;

    if (t < 4 * FINE_PER_COARSE) ((int*)hist)[t] = 0;
    __syncthreads();

    const unsigned* __restrict__ slab = coarse + (size_t)cb * CCAP;

    for (int i = beg + t; i < end; i += 256) {
        unsigned e = slab[i];
        atomicAdd(&hist[w][(e >> 17) >> 6], 1);
    }
    __syncthreads();

    if (t < FINE_PER_COARSE) {
        int c0 = hist[0][t], c1 = hist[1][t];
        int c2 = hist[2][t], c3 = hist[3][t];
        int tot = c0 + c1 + c2 + c3;
        int fb = cb * FINE_PER_COARSE + t;
        int b0 = tot ? atomicAdd(&fcursor[fb * CPAD], tot) : 0;
        wbase[0][t] = b0;
        wbase[1][t] = b0 + c0;
        wbase[2][t] = b0 + c0 + c1;
        wbase[3][t] = b0 + c0 + c1 + c2;
    }
    __syncthreads();

    for (int i = beg + t; i < end; i += 256) {
        unsigned e = slab[i];
        unsigned cl = e >> 17;
        int fb_loc = cl >> 6;
        int pos = atomicSub(&hist[w][fb_loc], 1) - 1;
        size_t fb = (size_t)cb * FINE_PER_COARSE + fb_loc;
        fine[fb * FCAP + wbase[w][fb_loc] + pos] =
            (e & 0x1FFFFu) | ((cl & 63u) << 17);
    }
}

// ---------------------------------------------------------------------------
// Fused sort + gather: one 512-thread block per fine bucket.
// Sort: slab entries staged in registers (<=3/thread), LDS int-atomic
//       counting sort over 64 local nodes; single-wave __shfl_up prefix scan.
// Gather: 8 lanes per node; lane loads uint4 (8 fp16 feats) -> one wave-instr
//       = 8 rows x 128 B. 4-edge unroll for MLP (latency-bound).
// Epilogue: out = tanh(acc + z), z fp16 from ws.
// ---------------------------------------------------------------------------
__global__ __launch_bounds__(512) void sortgather_kernel(
    const ushort_t* __restrict__ y, const ushort_t* __restrict__ z,
    const unsigned* __restrict__ part, const int* __restrict__ cursor,
    float* __restrict__ out, int N)
{
    __shared__ int sorted[SORT_CAP];
    __shared__ int hist[RB];
    __shared__ int cur[RB];
    __shared__ int begL[RB];

    int b = blockIdx.x;
    int t = threadIdx.x;
    int cnt = cursor[b * CPAD];
    if (cnt > SORT_CAP) cnt = SORT_CAP;   // unreachable (max ~950)
    const unsigned* __restrict__ slab = part + (size_t)b * FCAP;

    // stage slab entries in registers (SORT_CAP = 3*512)
    unsigned e0 = 0, e1 = 0, e2 = 0;
    int i0 = t, i1 = t + 512, i2 = t + 1024;
    if (i0 < cnt) e0 = slab[i0];
    if (i1 < cnt) e1 = slab[i1];
    if (i2 < cnt) e2 = slab[i2];

    if (t < RB) hist[t] = 0;
    __syncthreads();

    if (i0 < cnt) atomicAdd(&hist[e0 >> 17], 1);
    if (i1 < cnt) atomicAdd(&hist[e1 >> 17], 1);
    if (i2 < cnt) atomicAdd(&hist[e2 >> 17], 1);
    __syncthreads();

    // exclusive prefix over 64 counters: wave-0 shfl scan, no barriers inside
    if (t < RB) {
        int v = hist[t];
        int inc = v;
#pragma unroll
        for (int off = 1; off < RB; off <<= 1) {
            int n = __shfl_up(inc, off, RB);
            if (t >= off) inc += n;
        }
        int ex = inc - v;
        cur[t] = ex;
        begL[t] = ex;
    }
    __syncthreads();

    if (i0 < cnt) { int p = atomicAdd(&cur[e0 >> 17], 1); sorted[p] = (int)(e0 & 0x1FFFF); }
    if (i1 < cnt) { int p = atomicAdd(&cur[e1 >> 17], 1); sorted[p] = (int)(e1 & 0x1FFFF); }
    if (i2 < cnt) { int p = atomicAdd(&cur[e2 >> 17], 1); sorted[p] = (int)(e2 & 0x1FFFF); }
    __syncthreads();

    // ---- gather phase: group g (8 lanes) owns node g ----
    const int g = t >> 3;     // local node 0..63
    const int f = t & 7;      // feature slice: halves 8f..8f+7
    int myBeg = begL[g];
    int myDeg = hist[g];

    float2 acc0 = make_float2(0.f, 0.f), acc1 = acc0, acc2 = acc0, acc3 = acc0;

    int i = 0;
    for (; i + 4 <= myDeg; i += 4) {
        int s0 = sorted[myBeg + i];
        int s1 = sorted[myBeg + i + 1];
        int s2 = sorted[myBeg + i + 2];
        int s3 = sorted[myBeg + i + 3];
        uint4 r0 = ((const uint4*)(y + (size_t)s0 * D))[f];
        uint4 r1 = ((const uint4*)(y + (size_t)s1 * D))[f];
        uint4 r2 = ((const uint4*)(y + (size_t)s2 * D))[f];
        uint4 r3 = ((const uint4*)(y + (size_t)s3 * D))[f];
#define ACC(r) { \
        float2 c0 = __half22float2(*(const __half2*)&(r).x); \
        float2 c1 = __half22float2(*(const __half2*)&(r).y); \
        float2 c2 = __half22float2(*(const __half2*)&(r).z); \
        float2 c3 = __half22float2(*(const __half2*)&(r).w); \
        acc0.x += c0.x; acc0.y += c0.y; acc1.x += c1.x; acc1.y += c1.y; \
        acc2.x += c2.x; acc2.y += c2.y; acc3.x += c3.x; acc3.y += c3.y; }
        ACC(r0) ACC(r1) ACC(r2) ACC(r3)
    }
    for (; i < myDeg; i++) {
        int s = sorted[myBeg + i];
        uint4 r = ((const uint4*)(y + (size_t)s * D))[f];
        ACC(r)
    }
#undef ACC

    long gn = (long)b * RB + g;
    if (gn < N) {
        uint4 zr = ((const uint4*)(z + (size_t)gn * D))[f];
        float2 z0 = __half22float2(*(const __half2*)&zr.x);
        float2 z1 = __half22float2(*(const __half2*)&zr.y);
        float2 z2 = __half22float2(*(const __half2*)&zr.z);
        float2 z3 = __half22float2(*(const __half2*)&zr.w);
        float4 o0, o1;
        o0.x = tanhf(acc0.x + z0.x); o0.y = tanhf(acc0.y + z0.y);
        o0.z = tanhf(acc1.x + z1.x); o0.w = tanhf(acc1.y + z1.y);
        o1.x = tanhf(acc2.x + z2.x); o1.y = tanhf(acc2.y + z2.y);
        o1.z = tanhf(acc3.x + z3.x); o1.w = tanhf(acc3.y + z3.y);
        float4* op = (float4*)(out + gn * D);
        op[2 * f] = o0;
        op[2 * f + 1] = o1;
    }
}

extern "C" void kernel_launch(void* const* d_in, const int* in_sizes, int n_in,
                              void* d_out, int out_size, void* d_ws, size_t ws_size,
                              hipStream_t stream) {
    const float* x   = (const float*)d_in[0];
    const int* ei    = (const int*)d_in[1];   // [2,E] int32
    const float* W_l = (const float*)d_in[2];
    const float* b_l = (const float*)d_in[3];
    const float* W_r = (const float*)d_in[4];
    float* out = (float*)d_out;

    const int N = N_NODES;
    const int E = N_EDGES;
    const int* src = ei;
    const int* dst = ei + E;

    // workspace layout (ws is 268 MB)
    char* ws = (char*)d_ws;
    ushort_t* y      = (ushort_t*)(ws);                  // 12,800,000 B
    ushort_t* z      = (ushort_t*)(ws + 12800000);       // 12,800,000 B
    unsigned* coarse = (unsigned*)(ws + 25600000);       // NCB*CCAP*4 = 5,619,712 B
    unsigned* fine   = (unsigned*)(ws + 31219712);       // NB*FCAP*4 = 9,603,072 B
    int* ccursor     = (int*)(ws + 40822784);            // 49*64 B = 3,136 B (line-padded)
    int* fcursor     = (int*)(ws + 40825920);            // 1563*64 B = 100,032 B (line-padded)

    // zero both padded cursor arrays (adjacent): 3,136 + 100,032 B
    hipMemsetAsync(ccursor, 0, 103168, stream);

    partA_kernel<<<PARTA_BLOCKS, 256, 0, stream>>>(src, dst, ccursor, coarse, E);
    pre_kernel<<<PRE_BLOCKS, 256, 0, stream>>>(x, W_l, b_l, W_r, y, z, N);
    partB_kernel<<<NCB * SEGS, 256, 0, stream>>>(coarse, ccursor, fcursor, fine);
    sortgather_kernel<<<NB, 512, 0, stream>>>(y, z, fine, fcursor, out, N);
}

// Round 5
// 149.827 us; speedup vs baseline: 1.1100x; 1.1100x over previous
//
#include <hip/hip_runtime.h>
#include <hip/hip_bf16.h>
#include <hip/hip_fp16.h>

#define N_NODES 100000
#define D 64
#define N_EDGES 1250000

// fine buckets (sortgather granularity)
#define RB 64                   // nodes per fine bucket (dst>>6)
#define NB 1563                 // ceil(N / 64)
#define FCAP 1536               // fine slab capacity; mean 800, max ~950
#define SORT_CAP 1536

// coarse buckets (partition pass A)
#define CB_SHIFT 11             // 2048 nodes per coarse bucket
#define NCB 49                  // ceil(N / 2048)
#define CCAP 28672              // mean 25510, sigma ~158 -> +20 sigma
#define FINE_PER_COARSE 32      // 2048/64

// cursor padding: one counter per 64B cache line (round-1: packed cursors
// shared 4 lines across all blocks' global atomics).
#define CPAD 16                 // ints per cursor slot (64 B)

#define EPB 8192                // edges per pass-A block (runs of ~167/bucket)
#define PARTA_BLOCKS ((N_EDGES + EPB - 1) / EPB)   // 153
#define SEGS 16                 // pass-B blocks per coarse bucket
#define SEG_CAP 1792            // ceil(CCAP/SEGS)

#define TN 64                   // nodes per pre block
#define PRE_BLOCKS 1563         // ceil(N / 64)
#define FUSED_BLOCKS (PARTA_BLOCKS + PRE_BLOCKS)

#define XP 72                   // LDS fp16 row stride (64 + 8 pad)

// dynamic smem union: pre role 27,648 B; partA role 2,560 + 32,768 B
#define SMEM_BYTES 35328

typedef unsigned short ushort_t;
typedef _Float16 half_t;
typedef __attribute__((ext_vector_type(8))) _Float16 half8;
typedef __attribute__((ext_vector_type(4))) float floatx4;

// ---------------------------------------------------------------------------
// Fused pre-transform + partition pass A (re-fused: round-4 split cost +22us;
// partA's latency-exposed tail hides inside pre's 1563 blocks).
//
// partA role (blocks 0..152): ROUND-4 LESSON: scattered 4-B global writes
//   (each wave-store touches ~45 L2 lines) made partA ~40us/block. Now:
//   LDS counting sort of the block's 8192 edges by coarse bucket, then a
//   streaming sweep writes contiguous ~668-B runs per bucket (full lines).
// pre role (blocks 153..): [Y|Z] = X @ [W_l|W_r] via fp16 MFMA.
//   ROUND-4 LESSON: lane-packed uint2 stores scatter 16 lines/instr. Now:
//   acc staged into LDS (reusing the dead sXh buffer) and swept out as full
//   128-B rows -> each wave-store = 8 dense lines.
// ---------------------------------------------------------------------------
__global__ __launch_bounds__(256) void pre_part_kernel(
    const float* __restrict__ x, const float* __restrict__ W_l,
    const float* __restrict__ b_l, const float* __restrict__ W_r,
    ushort_t* __restrict__ y, ushort_t* __restrict__ z,
    const int* __restrict__ src, const int* __restrict__ dst,
    int* __restrict__ ccursor, unsigned* __restrict__ coarse,
    int N, int E)
{
    extern __shared__ char smem[];
    int t = threadIdx.x;

    if (blockIdx.x < PARTA_BLOCKS) {
        // ---------------- partA role: LDS counting sort + coalesced sweep ---
        int* hist4       = (int*)smem;             // [4][NCB], 784 B (pad 1024)
        int* lbase       = (int*)(smem + 1024);    // [64] local excl. base (+pad=lim)
        int* gbase       = (int*)(smem + 1280);    // [NCB] global reserved base
        int* lwb         = (int*)(smem + 1536);    // [4][NCB] per-wave local base
        unsigned* sortedL = (unsigned*)(smem + 2560); // [EPB] 32,768 B
        const int w = t >> 6;

        if (t < 4 * NCB) hist4[t] = 0;
        __syncthreads();

        int base = blockIdx.x * EPB;
        int lim = E - base; if (lim > EPB) lim = EPB;

        for (int i = t; i < lim; i += 256)
            atomicAdd(&hist4[w * NCB + (dst[base + i] >> CB_SHIFT)], 1);
        __syncthreads();

        if (t < 64) {   // wave 0: block scan + global reserve
            int c0 = 0, c1 = 0, c2 = 0, c3 = 0, tot = 0;
            if (t < NCB) {
                c0 = hist4[t]; c1 = hist4[NCB + t];
                c2 = hist4[2 * NCB + t]; c3 = hist4[3 * NCB + t];
                tot = c0 + c1 + c2 + c3;
            }
            int inc = tot;
#pragma unroll
            for (int off = 1; off < 64; off <<= 1) {
                int n = __shfl_up(inc, off, 64);
                if (t >= off) inc += n;
            }
            int ex = inc - tot;
            if (t < NCB) {
                lbase[t] = ex;
                gbase[t] = tot ? atomicAdd(&ccursor[t * CPAD], tot) : 0;
                lwb[t]           = ex;
                lwb[NCB + t]     = ex + c0;
                lwb[2 * NCB + t] = ex + c0 + c1;
                lwb[3 * NCB + t] = ex + c0 + c1 + c2;
            } else {
                lbase[t] = lim;   // sentinel pad for binary search
            }
        }
        __syncthreads();

        for (int i = t; i < lim; i += 256) {
            int d = dst[base + i];
            int s = src[base + i];
            int b = d >> CB_SHIFT;
            int pos = atomicSub(&hist4[w * NCB + b], 1) - 1;
            sortedL[lwb[w * NCB + b] + pos] =
                (unsigned)s | ((unsigned)(d & ((1 << CB_SHIFT) - 1)) << 17);
        }
        __syncthreads();

        // sweep: element i -> bucket = max b with lbase[b] <= i (empty-safe)
        for (int i = t; i < lim; i += 256) {
            int lo = 0;
#pragma unroll
            for (int s2 = 32; s2; s2 >>= 1) {
                int c = lo + s2;
                if (c < 64 && lbase[c] <= i) lo = c;
            }
            coarse[(size_t)lo * CCAP + gbase[lo] + (i - lbase[lo])] = sortedL[i];
        }
        return;
    }

    // ---------------- pre role (MFMA, LDS-staged coalesced output) ----------
    half_t* sWt = (half_t*)smem;            // [128*XP] W^T fp16, 18,432 B
    half_t* sXh = (half_t*)(smem + 18432);  // [TN*XP] X fp16; reused as Y/Z stage

    for (int i = t; i < 64 * 64; i += 256) {
        int k = i >> 6, c = i & 63;
        sWt[c * XP + k]        = (half_t)W_l[i];
        sWt[(64 + c) * XP + k] = (half_t)W_r[i];
    }

    long base = (long)(blockIdx.x - PARTA_BLOCKS) * TN;
    for (int i = t; i < TN * 16; i += 256) {   // 64 nodes x 16 float4
        int n = i >> 4, q = i & 15;
        long node = base + n;
        float4 v = make_float4(0.f, 0.f, 0.f, 0.f);
        if (node < N) v = ((const float4*)(x + node * D))[q];
        half_t* p = &sXh[n * XP + q * 4];
        p[0] = (half_t)v.x; p[1] = (half_t)v.y;
        p[2] = (half_t)v.z; p[3] = (half_t)v.w;
    }
    __syncthreads();

    const int lane  = t & 63;
    const int w     = t >> 6;        // wave id = node-tile 0..3
    const int col16 = lane & 15;
    const int quad  = lane >> 4;

    // X fragment (B operand): wave w reads ONLY its own 16 rows
    const int nrow = w * 16 + col16;
    half8 xb0 = *(half8*)&sXh[nrow * XP + quad * 8];
    half8 xb1 = *(half8*)&sXh[nrow * XP + 32 + quad * 8];

    // z-bias: bq[j] = b_l[j*16 + quad*4 .. +3]
    float4 bq[4];
#pragma unroll
    for (int j = 0; j < 4; j++) bq[j] = *(const float4*)(b_l + j * 16 + quad * 4);

    // --- Y: ct 0..3. Stage acc into sXh[own rows] (reads above are in regs;
    //     same-wave DS ordering makes this barrier-free). ---
#pragma unroll
    for (int ct = 0; ct < 4; ct++) {
        int c = ct * 16 + col16;
        half8 wa0 = *(half8*)&sWt[c * XP + quad * 8];
        half8 wa1 = *(half8*)&sWt[c * XP + 32 + quad * 8];
        floatx4 acc = {0.f, 0.f, 0.f, 0.f};
        acc = __builtin_amdgcn_mfma_f32_16x16x32_f16(wa0, xb0, acc, 0, 0, 0);
        acc = __builtin_amdgcn_mfma_f32_16x16x32_f16(wa1, xb1, acc, 0, 0, 0);
        union { half_t h[4]; uint2 u; } pk;
        pk.h[0] = (half_t)acc[0]; pk.h[1] = (half_t)acc[1];
        pk.h[2] = (half_t)acc[2]; pk.h[3] = (half_t)acc[3];
        // D: row=quad*4+r -> outcol ct*16+quad*4+r ; col=col16 -> node
        *(uint2*)&sXh[(w * 16 + col16) * XP + ct * 16 + quad * 4] = pk.u;
    }
    __syncthreads();

    // Y sweep: full 128-B rows, 8 lanes/row -> 8 dense lines per wave-store
    for (int c2 = t; c2 < TN * 8; c2 += 256) {
        int row = c2 >> 3, f = c2 & 7;
        if (base + row < N)
            *(uint4*)(y + (base + row) * D + f * 8) = *(uint4*)&sXh[row * XP + f * 8];
    }
    __syncthreads();

    // --- Z: ct 4..7 with bias ---
#pragma unroll
    for (int ct = 4; ct < 8; ct++) {
        int c = ct * 16 + col16;
        half8 wa0 = *(half8*)&sWt[c * XP + quad * 8];
        half8 wa1 = *(half8*)&sWt[c * XP + 32 + quad * 8];
        floatx4 acc = {0.f, 0.f, 0.f, 0.f};
        acc = __builtin_amdgcn_mfma_f32_16x16x32_f16(wa0, xb0, acc, 0, 0, 0);
        acc = __builtin_amdgcn_mfma_f32_16x16x32_f16(wa1, xb1, acc, 0, 0, 0);
        float4 bv = bq[ct - 4];
        union { half_t h[4]; uint2 u; } pk;
        pk.h[0] = (half_t)(acc[0] + bv.x); pk.h[1] = (half_t)(acc[1] + bv.y);
        pk.h[2] = (half_t)(acc[2] + bv.z); pk.h[3] = (half_t)(acc[3] + bv.w);
        *(uint2*)&sXh[(w * 16 + col16) * XP + (ct - 4) * 16 + quad * 4] = pk.u;
    }
    __syncthreads();

    for (int c2 = t; c2 < TN * 8; c2 += 256) {
        int row = c2 >> 3, f = c2 & 7;
        if (base + row < N)
            *(uint4*)(z + (base + row) * D + f * 8) = *(uint4*)&sXh[row * XP + f * 8];
    }
}

// ---------------------------------------------------------------------------
// Partition pass B: 16 segment-blocks per coarse bucket. Same LDS-sort +
// coalesced-sweep rework: runs of ~56 entries (224 B) instead of scattered
// 4-B writes. Repacks src | rowLocal<<17.
// ---------------------------------------------------------------------------
__global__ __launch_bounds__(256) void partB_kernel(
    const unsigned* __restrict__ coarse, const int* __restrict__ ccursor,
    int* __restrict__ fcursor, unsigned* __restrict__ fine)
{
    __shared__ int hist4[4 * FINE_PER_COARSE];
    __shared__ int lbase2[FINE_PER_COARSE];
    __shared__ int gbase2[FINE_PER_COARSE];
    __shared__ int lwb2[4 * FINE_PER_COARSE];
    __shared__ unsigned sortedL[SEG_CAP];

    int cb = blockIdx.x >> 4;        // SEGS = 16
    int seg = blockIdx.x & 15;
    int t = threadIdx.x;
    const int w = t >> 6;

    int cnt = ccursor[cb * CPAD];
    int segLen = (cnt + SEGS - 1) / SEGS;
    int beg = seg * segLen;
    int end = beg + segLen; if (end > cnt) end = cnt;
    int lim = end - beg; if (lim < 0) lim = 0;

    if (t < 4 * FINE_PER_COARSE) hist4[t] = 0;
    __syncthreads();

    const unsigned* __restrict__ slab = coarse + (size_t)cb * CCAP + beg;

    for (int i = t; i < lim; i += 256)
        atomicAdd(&hist4[w * FINE_PER_COARSE + ((slab[i] >> 17) >> 6)], 1);
    __syncthreads();

    if (t < 64) {
        int c0 = 0, c1 = 0, c2 = 0, c3 = 0, tot = 0;
        if (t < FINE_PER_COARSE) {
            c0 = hist4[t]; c1 = hist4[FINE_PER_COARSE + t];
            c2 = hist4[2 * FINE_PER_COARSE + t]; c3 = hist4[3 * FINE_PER_COARSE + t];
            tot = c0 + c1 + c2 + c3;
        }
        int inc = tot;
#pragma unroll
        for (int off = 1; off < 32; off <<= 1) {
            int n = __shfl_up(inc, off, 64);
            if (t >= off) inc += n;
        }
        int ex = inc - tot;
        if (t < FINE_PER_COARSE) {
            lbase2[t] = ex;
            int fb = cb * FINE_PER_COARSE + t;
            gbase2[t] = tot ? atomicAdd(&fcursor[fb * CPAD], tot) : 0;
            lwb2[t]                       = ex;
            lwb2[FINE_PER_COARSE + t]     = ex + c0;
            lwb2[2 * FINE_PER_COARSE + t] = ex + c0 + c1;
            lwb2[3 * FINE_PER_COARSE + t] = ex + c0 + c1 + c2;
        }
    }
    __syncthreads();

    for (int i = t; i < lim; i += 256) {
        unsigned e = slab[i];
        unsigned cl = e >> 17;
        int loc = cl >> 6;
        int pos = atomicSub(&hist4[w * FINE_PER_COARSE + loc], 1) - 1;
        sortedL[lwb2[w * FINE_PER_COARSE + loc] + pos] =
            (e & 0x1FFFFu) | ((cl & 63u) << 17);
    }
    __syncthreads();

    for (int i = t; i < lim; i += 256) {
        int lo = 0;
#pragma unroll
        for (int s2 = 16; s2; s2 >>= 1) {
            int c = lo + s2;
            if (c < FINE_PER_COARSE && lbase2[c] <= i) lo = c;
        }
        fine[((size_t)cb * FINE_PER_COARSE + lo) * FCAP + gbase2[lo] + (i - lbase2[lo])]
            = sortedL[i];
    }
}

// ---------------------------------------------------------------------------
// Fused sort + gather: one 512-thread block per fine bucket. (Unchanged.)
// ---------------------------------------------------------------------------
__global__ __launch_bounds__(512) void sortgather_kernel(
    const ushort_t* __restrict__ y, const ushort_t* __restrict__ z,
    const unsigned* __restrict__ part, const int* __restrict__ cursor,
    float* __restrict__ out, int N)
{
    __shared__ int sorted[SORT_CAP];
    __shared__ int hist[RB];
    __shared__ int cur[RB];
    __shared__ int begL[RB];

    int b = blockIdx.x;
    int t = threadIdx.x;
    int cnt = cursor[b * CPAD];
    if (cnt > SORT_CAP) cnt = SORT_CAP;   // unreachable (max ~950)
    const unsigned* __restrict__ slab = part + (size_t)b * FCAP;

    unsigned e0 = 0, e1 = 0, e2 = 0;
    int i0 = t, i1 = t + 512, i2 = t + 1024;
    if (i0 < cnt) e0 = slab[i0];
    if (i1 < cnt) e1 = slab[i1];
    if (i2 < cnt) e2 = slab[i2];

    if (t < RB) hist[t] = 0;
    __syncthreads();

    if (i0 < cnt) atomicAdd(&hist[e0 >> 17], 1);
    if (i1 < cnt) atomicAdd(&hist[e1 >> 17], 1);
    if (i2 < cnt) atomicAdd(&hist[e2 >> 17], 1);
    __syncthreads();

    if (t < RB) {
        int v = hist[t];
        int inc = v;
#pragma unroll
        for (int off = 1; off < RB; off <<= 1) {
            int n = __shfl_up(inc, off, RB);
            if (t >= off) inc += n;
        }
        int ex = inc - v;
        cur[t] = ex;
        begL[t] = ex;
    }
    __syncthreads();

    if (i0 < cnt) { int p = atomicAdd(&cur[e0 >> 17], 1); sorted[p] = (int)(e0 & 0x1FFFF); }
    if (i1 < cnt) { int p = atomicAdd(&cur[e1 >> 17], 1); sorted[p] = (int)(e1 & 0x1FFFF); }
    if (i2 < cnt) { int p = atomicAdd(&cur[e2 >> 17], 1); sorted[p] = (int)(e2 & 0x1FFFF); }
    __syncthreads();

    const int g = t >> 3;
    const int f = t & 7;
    int myBeg = begL[g];
    int myDeg = hist[g];

    float2 acc0 = make_float2(0.f, 0.f), acc1 = acc0, acc2 = acc0, acc3 = acc0;

    int i = 0;
    for (; i + 4 <= myDeg; i += 4) {
        int s0 = sorted[myBeg + i];
        int s1 = sorted[myBeg + i + 1];
        int s2 = sorted[myBeg + i + 2];
        int s3 = sorted[myBeg + i + 3];
        uint4 r0 = ((const uint4*)(y + (size_t)s0 * D))[f];
        uint4 r1 = ((const uint4*)(y + (size_t)s1 * D))[f];
        uint4 r2 = ((const uint4*)(y + (size_t)s2 * D))[f];
        uint4 r3 = ((const uint4*)(y + (size_t)s3 * D))[f];
#define ACC(r) { \
        float2 c0 = __half22float2(*(const __half2*)&(r).x); \
        float2 c1 = __half22float2(*(const __half2*)&(r).y); \
        float2 c2 = __half22float2(*(const __half2*)&(r).z); \
        float2 c3 = __half22float2(*(const __half2*)&(r).w); \
        acc0.x += c0.x; acc0.y += c0.y; acc1.x += c1.x; acc1.y += c1.y; \
        acc2.x += c2.x; acc2.y += c2.y; acc3.x += c3.x; acc3.y += c3.y; }
        ACC(r0) ACC(r1) ACC(r2) ACC(r3)
    }
    for (; i < myDeg; i++) {
        int s = sorted[myBeg + i];
        uint4 r = ((const uint4*)(y + (size_t)s * D))[f];
        ACC(r)
    }
#undef ACC

    long gn = (long)b * RB + g;
    if (gn < N) {
        uint4 zr = ((const uint4*)(z + (size_t)gn * D))[f];
        float2 z0 = __half22float2(*(const __half2*)&zr.x);
        float2 z1 = __half22float2(*(const __half2*)&zr.y);
        float2 z2 = __half22float2(*(const __half2*)&zr.z);
        float2 z3 = __half22float2(*(const __half2*)&zr.w);
        float4 o0, o1;
        o0.x = tanhf(acc0.x + z0.x); o0.y = tanhf(acc0.y + z0.y);
        o0.z = tanhf(acc1.x + z1.x); o0.w = tanhf(acc1.y + z1.y);
        o1.x = tanhf(acc2.x + z2.x); o1.y = tanhf(acc2.y + z2.y);
        o1.z = tanhf(acc3.x + z3.x); o1.w = tanhf(acc3.y + z3.y);
        float4* op = (float4*)(out + gn * D);
        op[2 * f] = o0;
        op[2 * f + 1] = o1;
    }
}

extern "C" void kernel_launch(void* const* d_in, const int* in_sizes, int n_in,
                              void* d_out, int out_size, void* d_ws, size_t ws_size,
                              hipStream_t stream) {
    const float* x   = (const float*)d_in[0];
    const int* ei    = (const int*)d_in[1];   // [2,E] int32
    const float* W_l = (const float*)d_in[2];
    const float* b_l = (const float*)d_in[3];
    const float* W_r = (const float*)d_in[4];
    float* out = (float*)d_out;

    const int N = N_NODES;
    const int E = N_EDGES;
    const int* src = ei;
    const int* dst = ei + E;

    // workspace layout (ws is 268 MB)
    char* ws = (char*)d_ws;
    ushort_t* y      = (ushort_t*)(ws);                  // 12,800,000 B
    ushort_t* z      = (ushort_t*)(ws + 12800000);       // 12,800,000 B
    unsigned* coarse = (unsigned*)(ws + 25600000);       // NCB*CCAP*4 = 5,619,712 B
    unsigned* fine   = (unsigned*)(ws + 31219712);       // NB*FCAP*4 = 9,603,072 B
    int* ccursor     = (int*)(ws + 40822784);            // 49*64 B (line-padded)
    int* fcursor     = (int*)(ws + 40825920);            // 1563*64 B (line-padded)

    // zero both padded cursor arrays (adjacent): 3,136 + 100,032 B
    hipMemsetAsync(ccursor, 0, 103168, stream);

    pre_part_kernel<<<FUSED_BLOCKS, 256, SMEM_BYTES, stream>>>(
        x, W_l, b_l, W_r, y, z, src, dst, ccursor, coarse, N, E);
    partB_kernel<<<NCB * SEGS, 256, 0, stream>>>(coarse, ccursor, fcursor, fine);
    sortgather_kernel<<<NB, 512, 0, stream>>>(y, z, fine, fcursor, out, N);
}

// Round 6
// 146.144 us; speedup vs baseline: 1.1379x; 1.0252x over previous
//
#include <hip/hip_runtime.h>
#include <hip/hip_bf16.h>
#include <hip/hip_fp16.h>

#define N_NODES 100000
#define D 64
#define N_EDGES 1250000

// fine buckets (sortgather granularity)
#define RB 64                   // nodes per fine bucket (dst>>6)
#define NB 1563                 // ceil(N / 64)
#define FCAP 1536               // fine slab capacity; mean 800, max ~950
#define SORT_CAP 1536

// cursor padding: one counter per 64B cache line (round-1 lesson: packed
// cursors share L2 lines across all blocks' global atomics).
#define CPAD 16                 // ints per cursor slot (64 B)

#define EPB 8192                // edges per partition block
#define PART_BLOCKS ((N_EDGES + EPB - 1) / EPB)   // 153

#define TN 64                   // nodes per pre block
#define PRE_BLOCKS 1563         // ceil(N / 64)
#define FUSED_BLOCKS (PART_BLOCKS + PRE_BLOCKS)

#define XP 72                   // LDS fp16 row stride (64 + 8 pad)

// dynamic smem union: pre role 27,648 B; part role 12,656 B
#define SMEM_BYTES 27648

typedef unsigned short ushort_t;
typedef _Float16 half_t;
typedef __attribute__((ext_vector_type(8))) _Float16 half8;
typedef __attribute__((ext_vector_type(4))) float floatx4;

// ---------------------------------------------------------------------------
// Fused pre-transform + SINGLE-LEVEL partition.
//
// Round-5 lesson: pre_part has been 43-45us across FOUR different write/atomic
// strategies -> partition micro-optimization is dead. partB (coarse->fine
// repack, a full extra read+write of all edges + a dispatch) never justified
// itself: scattered vs coalesced partition writes measured identical (slabs
// are L3-resident). So: ONE pass, per-block LDS hist over ALL 1563 fine
// buckets (6.3 KB), reserve global ranges on padded fcursor, scatter direct.
//
// part role (blocks 0..152):   edges -> fine[bucket] slabs, src|(d&63)<<17
// pre role  (blocks 153..):    [Y|Z] = X @ [W_l|W_r] via fp16 MFMA,
//                              LDS-staged 128-B-row output sweeps (round 5).
// ---------------------------------------------------------------------------
__global__ __launch_bounds__(256) void pre_part_kernel(
    const float* __restrict__ x, const float* __restrict__ W_l,
    const float* __restrict__ b_l, const float* __restrict__ W_r,
    ushort_t* __restrict__ y, ushort_t* __restrict__ z,
    const int* __restrict__ src, const int* __restrict__ dst,
    int* __restrict__ fcursor, unsigned* __restrict__ fine,
    int N, int E)
{
    extern __shared__ char smem[];
    int t = threadIdx.x;

    if (blockIdx.x < PART_BLOCKS) {
        // ---------------- part role: single-level fine scatter ----------
        int* hist  = (int*)smem;            // [NB] 6,252 B
        int* gbase = (int*)(smem + 6400);   // [NB] 6,252 B

        for (int i = t; i < NB; i += 256) hist[i] = 0;
        __syncthreads();

        int base = blockIdx.x * EPB;
        int lim = E - base; if (lim > EPB) lim = EPB;

        for (int i = t; i < lim; i += 256)
            atomicAdd(&hist[dst[base + i] >> 6], 1);
        __syncthreads();

        for (int b = t; b < NB; b += 256) {
            int c = hist[b];
            gbase[b] = c ? atomicAdd(&fcursor[b * CPAD], c) : 0;
        }
        __syncthreads();

        for (int i = t; i < lim; i += 256) {
            int d = dst[base + i];
            int s = src[base + i];
            int bin = d >> 6;
            int pos = atomicSub(&hist[bin], 1) - 1;
            fine[(size_t)bin * FCAP + gbase[bin] + pos] =
                (unsigned)s | ((unsigned)(d & 63) << 17);
        }
        return;
    }

    // ---------------- pre role (MFMA, LDS-staged coalesced output) ----------
    half_t* sWt = (half_t*)smem;            // [128*XP] W^T fp16, 18,432 B
    half_t* sXh = (half_t*)(smem + 18432);  // [TN*XP] X fp16; reused as Y/Z stage

    for (int i = t; i < 64 * 64; i += 256) {
        int k = i >> 6, c = i & 63;
        sWt[c * XP + k]        = (half_t)W_l[i];
        sWt[(64 + c) * XP + k] = (half_t)W_r[i];
    }

    long base = (long)(blockIdx.x - PART_BLOCKS) * TN;
    for (int i = t; i < TN * 16; i += 256) {   // 64 nodes x 16 float4
        int n = i >> 4, q = i & 15;
        long node = base + n;
        float4 v = make_float4(0.f, 0.f, 0.f, 0.f);
        if (node < N) v = ((const float4*)(x + node * D))[q];
        half_t* p = &sXh[n * XP + q * 4];
        p[0] = (half_t)v.x; p[1] = (half_t)v.y;
        p[2] = (half_t)v.z; p[3] = (half_t)v.w;
    }
    __syncthreads();

    const int lane  = t & 63;
    const int w     = t >> 6;        // wave id = node-tile 0..3
    const int col16 = lane & 15;
    const int quad  = lane >> 4;

    // X fragment (B operand): wave w reads ONLY its own 16 rows
    const int nrow = w * 16 + col16;
    half8 xb0 = *(half8*)&sXh[nrow * XP + quad * 8];
    half8 xb1 = *(half8*)&sXh[nrow * XP + 32 + quad * 8];

    // z-bias: bq[j] = b_l[j*16 + quad*4 .. +3]
    float4 bq[4];
#pragma unroll
    for (int j = 0; j < 4; j++) bq[j] = *(const float4*)(b_l + j * 16 + quad * 4);

    // --- Y: ct 0..3. Stage acc into sXh[own rows] (xb already in regs;
    //     same-wave DS ordering makes this barrier-free). ---
#pragma unroll
    for (int ct = 0; ct < 4; ct++) {
        int c = ct * 16 + col16;
        half8 wa0 = *(half8*)&sWt[c * XP + quad * 8];
        half8 wa1 = *(half8*)&sWt[c * XP + 32 + quad * 8];
        floatx4 acc = {0.f, 0.f, 0.f, 0.f};
        acc = __builtin_amdgcn_mfma_f32_16x16x32_f16(wa0, xb0, acc, 0, 0, 0);
        acc = __builtin_amdgcn_mfma_f32_16x16x32_f16(wa1, xb1, acc, 0, 0, 0);
        union { half_t h[4]; uint2 u; } pk;
        pk.h[0] = (half_t)acc[0]; pk.h[1] = (half_t)acc[1];
        pk.h[2] = (half_t)acc[2]; pk.h[3] = (half_t)acc[3];
        // D: row=quad*4+r -> outcol ct*16+quad*4+r ; col=col16 -> node
        *(uint2*)&sXh[(w * 16 + col16) * XP + ct * 16 + quad * 4] = pk.u;
    }
    __syncthreads();

    // Y sweep: full 128-B rows, 8 lanes/row -> 8 dense lines per wave-store
    for (int c2 = t; c2 < TN * 8; c2 += 256) {
        int row = c2 >> 3, f = c2 & 7;
        if (base + row < N)
            *(uint4*)(y + (base + row) * D + f * 8) = *(uint4*)&sXh[row * XP + f * 8];
    }
    __syncthreads();

    // --- Z: ct 4..7 with bias ---
#pragma unroll
    for (int ct = 4; ct < 8; ct++) {
        int c = ct * 16 + col16;
        half8 wa0 = *(half8*)&sWt[c * XP + quad * 8];
        half8 wa1 = *(half8*)&sWt[c * XP + 32 + quad * 8];
        floatx4 acc = {0.f, 0.f, 0.f, 0.f};
        acc = __builtin_amdgcn_mfma_f32_16x16x32_f16(wa0, xb0, acc, 0, 0, 0);
        acc = __builtin_amdgcn_mfma_f32_16x16x32_f16(wa1, xb1, acc, 0, 0, 0);
        float4 bv = bq[ct - 4];
        union { half_t h[4]; uint2 u; } pk;
        pk.h[0] = (half_t)(acc[0] + bv.x); pk.h[1] = (half_t)(acc[1] + bv.y);
        pk.h[2] = (half_t)(acc[2] + bv.z); pk.h[3] = (half_t)(acc[3] + bv.w);
        *(uint2*)&sXh[(w * 16 + col16) * XP + (ct - 4) * 16 + quad * 4] = pk.u;
    }
    __syncthreads();

    for (int c2 = t; c2 < TN * 8; c2 += 256) {
        int row = c2 >> 3, f = c2 & 7;
        if (base + row < N)
            *(uint4*)(z + (base + row) * D + f * 8) = *(uint4*)&sXh[row * XP + f * 8];
    }
}

// ---------------------------------------------------------------------------
// Fused sort + gather: one 512-thread block per fine bucket. (Unchanged.)
// ---------------------------------------------------------------------------
__global__ __launch_bounds__(512) void sortgather_kernel(
    const ushort_t* __restrict__ y, const ushort_t* __restrict__ z,
    const unsigned* __restrict__ part, const int* __restrict__ cursor,
    float* __restrict__ out, int N)
{
    __shared__ int sorted[SORT_CAP];
    __shared__ int hist[RB];
    __shared__ int cur[RB];
    __shared__ int begL[RB];

    int b = blockIdx.x;
    int t = threadIdx.x;
    int cnt = cursor[b * CPAD];
    if (cnt > SORT_CAP) cnt = SORT_CAP;   // unreachable (max ~950)
    const unsigned* __restrict__ slab = part + (size_t)b * FCAP;

    unsigned e0 = 0, e1 = 0, e2 = 0;
    int i0 = t, i1 = t + 512, i2 = t + 1024;
    if (i0 < cnt) e0 = slab[i0];
    if (i1 < cnt) e1 = slab[i1];
    if (i2 < cnt) e2 = slab[i2];

    if (t < RB) hist[t] = 0;
    __syncthreads();

    if (i0 < cnt) atomicAdd(&hist[e0 >> 17], 1);
    if (i1 < cnt) atomicAdd(&hist[e1 >> 17], 1);
    if (i2 < cnt) atomicAdd(&hist[e2 >> 17], 1);
    __syncthreads();

    if (t < RB) {
        int v = hist[t];
        int inc = v;
#pragma unroll
        for (int off = 1; off < RB; off <<= 1) {
            int n = __shfl_up(inc, off, RB);
            if (t >= off) inc += n;
        }
        int ex = inc - v;
        cur[t] = ex;
        begL[t] = ex;
    }
    __syncthreads();

    if (i0 < cnt) { int p = atomicAdd(&cur[e0 >> 17], 1); sorted[p] = (int)(e0 & 0x1FFFF); }
    if (i1 < cnt) { int p = atomicAdd(&cur[e1 >> 17], 1); sorted[p] = (int)(e1 & 0x1FFFF); }
    if (i2 < cnt) { int p = atomicAdd(&cur[e2 >> 17], 1); sorted[p] = (int)(e2 & 0x1FFFF); }
    __syncthreads();

    const int g = t >> 3;
    const int f = t & 7;
    int myBeg = begL[g];
    int myDeg = hist[g];

    float2 acc0 = make_float2(0.f, 0.f), acc1 = acc0, acc2 = acc0, acc3 = acc0;

    int i = 0;
    for (; i + 4 <= myDeg; i += 4) {
        int s0 = sorted[myBeg + i];
        int s1 = sorted[myBeg + i + 1];
        int s2 = sorted[myBeg + i + 2];
        int s3 = sorted[myBeg + i + 3];
        uint4 r0 = ((const uint4*)(y + (size_t)s0 * D))[f];
        uint4 r1 = ((const uint4*)(y + (size_t)s1 * D))[f];
        uint4 r2 = ((const uint4*)(y + (size_t)s2 * D))[f];
        uint4 r3 = ((const uint4*)(y + (size_t)s3 * D))[f];
#define ACC(r) { \
        float2 c0 = __half22float2(*(const __half2*)&(r).x); \
        float2 c1 = __half22float2(*(const __half2*)&(r).y); \
        float2 c2 = __half22float2(*(const __half2*)&(r).z); \
        float2 c3 = __half22float2(*(const __half2*)&(r).w); \
        acc0.x += c0.x; acc0.y += c0.y; acc1.x += c1.x; acc1.y += c1.y; \
        acc2.x += c2.x; acc2.y += c2.y; acc3.x += c3.x; acc3.y += c3.y; }
        ACC(r0) ACC(r1) ACC(r2) ACC(r3)
    }
    for (; i < myDeg; i++) {
        int s = sorted[myBeg + i];
        uint4 r = ((const uint4*)(y + (size_t)s * D))[f];
        ACC(r)
    }
#undef ACC

    long gn = (long)b * RB + g;
    if (gn < N) {
        uint4 zr = ((const uint4*)(z + (size_t)gn * D))[f];
        float2 z0 = __half22float2(*(const __half2*)&zr.x);
        float2 z1 = __half22float2(*(const __half2*)&zr.y);
        float2 z2 = __half22float2(*(const __half2*)&zr.z);
        float2 z3 = __half22float2(*(const __half2*)&zr.w);
        float4 o0, o1;
        o0.x = tanhf(acc0.x + z0.x); o0.y = tanhf(acc0.y + z0.y);
        o0.z = tanhf(acc1.x + z1.x); o0.w = tanhf(acc1.y + z1.y);
        o1.x = tanhf(acc2.x + z2.x); o1.y = tanhf(acc2.y + z2.y);
        o1.z = tanhf(acc3.x + z3.x); o1.w = tanhf(acc3.y + z3.y);
        float4* op = (float4*)(out + gn * D);
        op[2 * f] = o0;
        op[2 * f + 1] = o1;
    }
}

extern "C" void kernel_launch(void* const* d_in, const int* in_sizes, int n_in,
                              void* d_out, int out_size, void* d_ws, size_t ws_size,
                              hipStream_t stream) {
    const float* x   = (const float*)d_in[0];
    const int* ei    = (const int*)d_in[1];   // [2,E] int32
    const float* W_l = (const float*)d_in[2];
    const float* b_l = (const float*)d_in[3];
    const float* W_r = (const float*)d_in[4];
    float* out = (float*)d_out;

    const int N = N_NODES;
    const int E = N_EDGES;
    const int* src = ei;
    const int* dst = ei + E;

    // workspace layout (ws is 268 MB)
    char* ws = (char*)d_ws;
    ushort_t* y    = (ushort_t*)(ws);                  // 12,800,000 B
    ushort_t* z    = (ushort_t*)(ws + 12800000);       // 12,800,000 B
    unsigned* fine = (unsigned*)(ws + 25600000);       // NB*FCAP*4 = 9,603,072 B
    int* fcursor   = (int*)(ws + 35203072);            // 1563*64 B = 100,032 B (line-padded)

    // zero padded fine cursors
    hipMemsetAsync(fcursor, 0, 100032, stream);

    pre_part_kernel<<<FUSED_BLOCKS, 256, SMEM_BYTES, stream>>>(
        x, W_l, b_l, W_r, y, z, src, dst, fcursor, fine, N, E);
    sortgather_kernel<<<NB, 512, 0, stream>>>(y, z, fine, fcursor, out, N);
}